// Round 2
// baseline (336.782 us; speedup 1.0000x reference)
//
#include <hip/hip_runtime.h>

// Attention_29231547416680: B=4, N=2048, CH=512, H=8, D=64, fp32 in/out.
// Strategy: split-bf16 (hi+lo) 3-MFMA fp32 emulation for all matmuls.
// K1: QKV projection GEMM -> ws (Q,K row-major per (b,h); V transposed)
// K2: flash attention, online softmax; mask dtype (1B bool vs 4B int/float)
//     detected at runtime from the data pattern.

typedef float f32x4 __attribute__((ext_vector_type(4)));
typedef short short8 __attribute__((ext_vector_type(8)));

#define MFMA(a, b, c) __builtin_amdgcn_mfma_f32_16x16x32_bf16((a), (b), (c), 0, 0, 0)

__device__ __forceinline__ unsigned short f2bf(float f) {
  unsigned int u = __float_as_uint(f);
  u += 0x7fffu + ((u >> 16) & 1u);  // round-to-nearest-even
  return (unsigned short)(u >> 16);
}
__device__ __forceinline__ float bf2f(unsigned short h) {
  return __uint_as_float(((unsigned int)h) << 16);
}
__device__ __forceinline__ void split_bf16(float f, unsigned short& hi, unsigned short& lo) {
  hi = f2bf(f);
  lo = f2bf(f - bf2f(hi));  // f - float(hi) is exact in fp32
}

// ---------------- Kernel 1: QKV projection ----------------
// out[m][c] = sum_k x[m][k] * W[c][k]   (x @ W^T), c = h*64+d
// Q,K stored [b][h][n][64]; V stored transposed [b][h][64][n].
__global__ __launch_bounds__(256) void proj_kernel(
    const float* __restrict__ x,
    const float* __restrict__ Wq, const float* __restrict__ Wk, const float* __restrict__ Wv,
    float* __restrict__ Qo, float* __restrict__ Ko, float* __restrict__ Vto) {
  const int tid = threadIdx.x;
  const int w = tid >> 6, l = tid & 63;
  const int m0 = blockIdx.x * 64;   // row tile (b,n flattened)
  const int h  = blockIdx.y;        // head = column block of 64
  const int z  = blockIdx.z;        // 0:Q 1:K 2:V
  const float* W = (z == 0) ? Wq : (z == 1) ? Wk : Wv;

  __shared__ __align__(16) unsigned short Ah[64][48], Al[64][48], Bh[64][48], Bl[64][48];

  const int rw = (w >> 1) * 32;  // wave's row quadrant
  const int cw = (w & 1) * 32;   // wave's col quadrant

  f32x4 acc[2][2] = {};

  for (int k0 = 0; k0 < 512; k0 += 32) {
    __syncthreads();
#pragma unroll
    for (int i = 0; i < 2; ++i) {
      int f = tid + i * 256;     // 0..511 float4 slots
      int row = f >> 3;          // 0..63
      int c4 = (f & 7) * 4;      // 0..28
      float4 va = *reinterpret_cast<const float4*>(&x[(size_t)(m0 + row) * 512 + k0 + c4]);
      float4 vb = *reinterpret_cast<const float4*>(&W[(size_t)(h * 64 + row) * 512 + k0 + c4]);
      unsigned short h0, l0, h1, l1, h2, l2, h3, l3;
      split_bf16(va.x, h0, l0); split_bf16(va.y, h1, l1);
      split_bf16(va.z, h2, l2); split_bf16(va.w, h3, l3);
      *reinterpret_cast<ushort4*>(&Ah[row][c4]) = make_ushort4(h0, h1, h2, h3);
      *reinterpret_cast<ushort4*>(&Al[row][c4]) = make_ushort4(l0, l1, l2, l3);
      split_bf16(vb.x, h0, l0); split_bf16(vb.y, h1, l1);
      split_bf16(vb.z, h2, l2); split_bf16(vb.w, h3, l3);
      *reinterpret_cast<ushort4*>(&Bh[row][c4]) = make_ushort4(h0, h1, h2, h3);
      *reinterpret_cast<ushort4*>(&Bl[row][c4]) = make_ushort4(l0, l1, l2, l3);
    }
    __syncthreads();

    short8 ah[2], al[2], bh[2], bl[2];
#pragma unroll
    for (int t = 0; t < 2; ++t) {
      ah[t] = *reinterpret_cast<const short8*>(&Ah[rw + t * 16 + (l & 15)][(l >> 4) * 8]);
      al[t] = *reinterpret_cast<const short8*>(&Al[rw + t * 16 + (l & 15)][(l >> 4) * 8]);
      bh[t] = *reinterpret_cast<const short8*>(&Bh[cw + t * 16 + (l & 15)][(l >> 4) * 8]);
      bl[t] = *reinterpret_cast<const short8*>(&Bl[cw + t * 16 + (l & 15)][(l >> 4) * 8]);
    }
#pragma unroll
    for (int tm = 0; tm < 2; ++tm)
#pragma unroll
      for (int tn = 0; tn < 2; ++tn) {
        acc[tm][tn] = MFMA(ah[tm], bh[tn], acc[tm][tn]);
        acc[tm][tn] = MFMA(ah[tm], bl[tn], acc[tm][tn]);
        acc[tm][tn] = MFMA(al[tm], bh[tn], acc[tm][tn]);
      }
  }

  // Store. C/D layout: col = lane&15, row = (lane>>4)*4 + reg.
#pragma unroll
  for (int tm = 0; tm < 2; ++tm)
#pragma unroll
    for (int tn = 0; tn < 2; ++tn) {
      int d = cw + tn * 16 + (l & 15);
      int mbase = m0 + rw + tm * 16 + (l >> 4) * 4;
      int b = mbase >> 11;
      int n = mbase & 2047;
      if (z == 2) {
        // Vt[b][h][d][n] : 4 consecutive n per lane -> float4 store
        *reinterpret_cast<float4*>(&Vto[((size_t)(b * 8 + h) * 64 + d) * 2048 + n]) =
            *reinterpret_cast<float4*>(&acc[tm][tn]);
      } else {
        float* O = (z == 0) ? Qo : Ko;
#pragma unroll
        for (int r = 0; r < 4; ++r) {
          O[((size_t)(b * 8 + h) * 2048 + (n + r)) * 64 + d] = acc[tm][tn][r];
        }
      }
    }
}

// ---------------- Kernel 2: flash attention ----------------
// grid (32 q-tiles, 32 bh), 256 threads = 4 waves, wave w owns q rows w*16..+15.
__global__ __launch_bounds__(256) void attn_kernel(
    const float* __restrict__ Q, const float* __restrict__ K, const float* __restrict__ Vt,
    const void* __restrict__ mask_raw, float* __restrict__ out) {
  const int tid = threadIdx.x;
  const int w = tid >> 6, l = tid & 63;
  const int q0 = blockIdx.x * 64;
  const int bh = blockIdx.y;
  const int b = bh >> 3, h = bh & 7;

  // ---- detect mask element width (1 byte bool vs 4 byte int32/float32) ----
  // int32 0/1 words are {0,1}; float32 0.0/1.0 words are {0,0x3f800000};
  // random 0/1 BYTES give words outside that set with P=7/8 per word.
  __shared__ int s_bad;
  if (tid == 0) s_bad = 0;
  __syncthreads();
  {
    const unsigned int* mw = (const unsigned int*)mask_raw;
    unsigned int w0 = mw[tid], w1 = mw[tid + 256];
    bool ok = (w0 == 0u || w0 == 1u || w0 == 0x3f800000u) &&
              (w1 == 0u || w1 == 1u || w1 == 0x3f800000u);
    if (!ok) s_bad = 1;
  }
  __syncthreads();
  const bool mask_is_word = (s_bad == 0);
  const unsigned char* M8 = (const unsigned char*)mask_raw + (size_t)b * 2048 * 2048;
  const unsigned int* M32 = (const unsigned int*)mask_raw + (size_t)b * 2048 * 2048;

  const float* Qb = Q + (size_t)bh * 2048 * 64;
  const float* Kb = K + (size_t)bh * 2048 * 64;
  const float* Vb = Vt + (size_t)bh * 64 * 2048;
  float* Ob = out + (size_t)b * 2048 * 512 + h * 64;

  union __align__(16) SA {
    float qf[64][64];                 // Q staging (transient)
    unsigned short kv[4][64][80];     // 0:Kh 1:Kl 2:Vh 3:Vl  (padded stride 80)
  };
  __shared__ SA sA;
  __shared__ __align__(16) unsigned short Pb[2][4][16][80];  // [hi/lo][wave][qrow][k]

  const float invT = 0.08838834764831845f;  // 1/sqrt(128)

  // ---- load Q tile, pre-scale by 1/TEMP ----
#pragma unroll
  for (int i = 0; i < 4; ++i) {
    int f = tid + i * 256;     // 0..1023 float4 slots
    int row = f >> 4;
    int c4 = (f & 15) * 4;
    float4 v = *reinterpret_cast<const float4*>(&Qb[(size_t)(q0 + row) * 64 + c4]);
    v.x *= invT; v.y *= invT; v.z *= invT; v.w *= invT;
    *reinterpret_cast<float4*>(&sA.qf[row][c4]) = v;
  }
  __syncthreads();

  // per-lane Q A-frags (row = l&15, k = (l>>4)*8 + j), kept in registers
  short8 qh[2], ql[2];
#pragma unroll
  for (int dc = 0; dc < 2; ++dc) {
#pragma unroll
    for (int j = 0; j < 8; ++j) {
      float qv = sA.qf[w * 16 + (l & 15)][dc * 32 + (l >> 4) * 8 + j];
      unsigned short hi, lo;
      split_bf16(qv, hi, lo);
      qh[dc][j] = (short)hi;
      ql[dc][j] = (short)lo;
    }
  }

  f32x4 o[4] = {};
  float mrun[4], lrun[4];
#pragma unroll
  for (int r = 0; r < 4; ++r) { mrun[r] = -1e30f; lrun[r] = 0.0f; }

  const int qrowbase = q0 + w * 16 + (l >> 4) * 4;

  for (int k0 = 0; k0 < 2048; k0 += 64) {
    __syncthreads();  // previous iteration fully done (also covers qf->kv overlay)

    // ---- stage K tile [64][64] and Vt tile [64 d][64 k] as hi/lo bf16 ----
#pragma unroll
    for (int i = 0; i < 4; ++i) {
      int f = tid + i * 256;   // 0..1023
      int row = f >> 4;        // 0..63
      int c4 = (f & 15) * 4;
      float4 kv4 = *reinterpret_cast<const float4*>(&Kb[(size_t)(k0 + row) * 64 + c4]);
      float4 vv4 = *reinterpret_cast<const float4*>(&Vb[(size_t)row * 2048 + k0 + c4]);
      unsigned short h0, l0, h1, l1, h2, l2, h3, l3;
      split_bf16(kv4.x, h0, l0); split_bf16(kv4.y, h1, l1);
      split_bf16(kv4.z, h2, l2); split_bf16(kv4.w, h3, l3);
      *reinterpret_cast<ushort4*>(&sA.kv[0][row][c4]) = make_ushort4(h0, h1, h2, h3);
      *reinterpret_cast<ushort4*>(&sA.kv[1][row][c4]) = make_ushort4(l0, l1, l2, l3);
      split_bf16(vv4.x, h0, l0); split_bf16(vv4.y, h1, l1);
      split_bf16(vv4.z, h2, l2); split_bf16(vv4.w, h3, l3);
      *reinterpret_cast<ushort4*>(&sA.kv[2][row][c4]) = make_ushort4(h0, h1, h2, h3);
      *reinterpret_cast<ushort4*>(&sA.kv[3][row][c4]) = make_ushort4(l0, l1, l2, l3);
    }
    __syncthreads();

    // ---- mask prefetch (overlaps with MFMAs below) ----
    unsigned char mbits[4][4];
    if (mask_is_word) {
#pragma unroll
      for (int r = 0; r < 4; ++r) {
        const unsigned int* mrow = M32 + (size_t)(qrowbase + r) * 2048 + k0 + (l & 15);
#pragma unroll
        for (int kt = 0; kt < 4; ++kt) mbits[r][kt] = (mrow[kt * 16] != 0u);
      }
    } else {
#pragma unroll
      for (int r = 0; r < 4; ++r) {
        const unsigned char* mrow = M8 + (size_t)(qrowbase + r) * 2048 + k0 + (l & 15);
#pragma unroll
        for (int kt = 0; kt < 4; ++kt) mbits[r][kt] = mrow[kt * 16];
      }
    }

    // ---- S = Q K^T (split-bf16: 3 MFMAs per product) ----
    f32x4 s[4] = {};
#pragma unroll
    for (int dc = 0; dc < 2; ++dc) {
#pragma unroll
      for (int kt = 0; kt < 4; ++kt) {
        short8 kh = *reinterpret_cast<const short8*>(
            &sA.kv[0][kt * 16 + (l & 15)][dc * 32 + (l >> 4) * 8]);
        short8 kl = *reinterpret_cast<const short8*>(
            &sA.kv[1][kt * 16 + (l & 15)][dc * 32 + (l >> 4) * 8]);
        s[kt] = MFMA(qh[dc], kh, s[kt]);
        s[kt] = MFMA(qh[dc], kl, s[kt]);
        s[kt] = MFMA(ql[dc], kh, s[kt]);
      }
    }

    // ---- masked online softmax (row lives in a 16-lane group) ----
#pragma unroll
    for (int r = 0; r < 4; ++r) {
      float sv[4];
#pragma unroll
      for (int kt = 0; kt < 4; ++kt) sv[kt] = mbits[r][kt] ? -1e30f : s[kt][r];
      float mx = fmaxf(fmaxf(sv[0], sv[1]), fmaxf(sv[2], sv[3]));
#pragma unroll
      for (int off = 1; off < 16; off <<= 1) mx = fmaxf(mx, __shfl_xor(mx, off));
      float mnew = fmaxf(mrun[r], mx);
      float scale = __expf(mrun[r] - mnew);  // finite: -1e30 - (-1e30) = 0
      float p[4], rs = 0.0f;
#pragma unroll
      for (int kt = 0; kt < 4; ++kt) {
        p[kt] = (sv[kt] <= -1e29f) ? 0.0f : __expf(sv[kt] - mnew);
        rs += p[kt];
      }
#pragma unroll
      for (int off = 1; off < 16; off <<= 1) rs += __shfl_xor(rs, off);
      lrun[r] = lrun[r] * scale + rs;
      mrun[r] = mnew;
#pragma unroll
      for (int dt = 0; dt < 4; ++dt) o[dt][r] *= scale;

      // P (hi/lo) -> per-wave LDS region for D-layout -> A-layout transpose
      int prow = (l >> 4) * 4 + r;
#pragma unroll
      for (int kt = 0; kt < 4; ++kt) {
        unsigned short hi, lo;
        split_bf16(p[kt], hi, lo);
        Pb[0][w][prow][kt * 16 + (l & 15)] = hi;
        Pb[1][w][prow][kt * 16 + (l & 15)] = lo;
      }
    }

    // ---- O += P V  (same-wave LDS write->read; compiler inserts lgkmcnt) ----
    short8 pah[2], pal[2];
#pragma unroll
    for (int kc = 0; kc < 2; ++kc) {
      pah[kc] = *reinterpret_cast<const short8*>(&Pb[0][w][l & 15][kc * 32 + (l >> 4) * 8]);
      pal[kc] = *reinterpret_cast<const short8*>(&Pb[1][w][l & 15][kc * 32 + (l >> 4) * 8]);
    }
#pragma unroll
    for (int dt = 0; dt < 4; ++dt) {
#pragma unroll
      for (int kc = 0; kc < 2; ++kc) {
        short8 vh = *reinterpret_cast<const short8*>(
            &sA.kv[2][dt * 16 + (l & 15)][kc * 32 + (l >> 4) * 8]);
        short8 vl = *reinterpret_cast<const short8*>(
            &sA.kv[3][dt * 16 + (l & 15)][kc * 32 + (l >> 4) * 8]);
        o[dt] = MFMA(pah[kc], vh, o[dt]);
        o[dt] = MFMA(pah[kc], vl, o[dt]);
        o[dt] = MFMA(pal[kc], vh, o[dt]);
      }
    }
  }

  // ---- epilogue: O / l ----
#pragma unroll
  for (int r = 0; r < 4; ++r) {
    float invl = lrun[r] > 0.0f ? 1.0f / lrun[r] : 0.0f;
    int qrow = qrowbase + r;
#pragma unroll
    for (int dt = 0; dt < 4; ++dt) {
      Ob[(size_t)qrow * 512 + dt * 16 + (l & 15)] = o[dt][r] * invl;
    }
  }
}

extern "C" void kernel_launch(void* const* d_in, const int* in_sizes, int n_in,
                              void* d_out, int out_size, void* d_ws, size_t ws_size,
                              hipStream_t stream) {
  const float* x = (const float*)d_in[0];
  const void* mask = d_in[1];  // bool: width detected at runtime in-kernel
  const float* Wq = (const float*)d_in[2];
  const float* Wk = (const float*)d_in[3];
  const float* Wv = (const float*)d_in[4];
  float* out = (float*)d_out;

  const size_t per = (size_t)4 * 8 * 2048 * 64;  // 4,194,304 floats each
  float* Qw = (float*)d_ws;
  float* Kw = Qw + per;
  float* Vtw = Kw + per;

  proj_kernel<<<dim3(128, 8, 3), 256, 0, stream>>>(x, Wq, Wk, Wv, Qw, Kw, Vtw);
  attn_kernel<<<dim3(32, 32), 256, 0, stream>>>(Qw, Kw, Vtw, mask, out);
}

// Round 3
// 277.602 us; speedup vs baseline: 1.2132x; 1.2132x over previous
//
#include <hip/hip_runtime.h>

// Attention_29231547416680: B=4, N=2048, CH=512, H=8, D=64, fp32 in/out.
// R3: pre-split bf16 hi/lo planes at projection; bit-packed mask; 128-row
//     q-tiles with 8 waves; XOR-swizzled LDS (T2), no padding.

typedef float f32x4 __attribute__((ext_vector_type(4)));
typedef short short8 __attribute__((ext_vector_type(8)));

#define MFMA(a, b, c) __builtin_amdgcn_mfma_f32_16x16x32_bf16((a), (b), (c), 0, 0, 0)

#define NBH 32      // B*H
#define NSEQ 2048
#define DH 64

__device__ __forceinline__ unsigned short f2bf(float f) {
  unsigned int u = __float_as_uint(f);
  u += 0x7fffu + ((u >> 16) & 1u);  // RTNE
  return (unsigned short)(u >> 16);
}
__device__ __forceinline__ float bf2f(unsigned short h) {
  return __uint_as_float(((unsigned int)h) << 16);
}
__device__ __forceinline__ void split_bf16(float f, unsigned short& hi, unsigned short& lo) {
  hi = f2bf(f);
  lo = f2bf(f - bf2f(hi));
}

// Swizzled LDS accessor for [R][64]-ushort tiles (row stride 128 B):
// byte = row*128 + colbyte, XOR'd by (row&7)<<4. Bijective per row; keeps
// 16B chunks intact (xor bits 4-6 only).
__device__ __forceinline__ void* lds_sw(void* base, int row, int colbyte) {
  return (void*)((char*)base + ((row * 128 + colbyte) ^ ((row & 7) << 4)));
}

// ---------------- mask bit-pack (with dtype width detection) ----------------
__global__ __launch_bounds__(256) void pack_mask(const void* __restrict__ mraw,
                                                 unsigned long long* __restrict__ Mp) {
  __shared__ int s_bad;
  if (threadIdx.x == 0) s_bad = 0;
  __syncthreads();
  const unsigned int* mw = (const unsigned int*)mraw;
  {
    unsigned int w0 = mw[threadIdx.x], w1 = mw[threadIdx.x + 256];
    bool ok = (w0 == 0u || w0 == 1u || w0 == 0x3f800000u) &&
              (w1 == 0u || w1 == 1u || w1 == 0x3f800000u);
    if (!ok) s_bad = 1;
  }
  __syncthreads();
  size_t e = (size_t)blockIdx.x * 256 + threadIdx.x;
  bool v;
  if (s_bad == 0) v = (mw[e] != 0u);                          // int32/float32 mask
  else            v = (((const unsigned char*)mraw)[e] != 0); // 1-byte bool mask
  unsigned long long bits = __ballot(v);
  if ((threadIdx.x & 63) == 0) Mp[e >> 6] = bits;
}

// ---------------- Kernel 1: QKV projection -> hi/lo bf16 planes ----------------
// Q: pre-scaled by 1/sqrt(128), [bh][n][64]; K: [bh][n][64]; V: transposed [bh][64][n].
__global__ __launch_bounds__(256) void proj_kernel(
    const float* __restrict__ x,
    const float* __restrict__ Wq, const float* __restrict__ Wk, const float* __restrict__ Wv,
    unsigned short* __restrict__ Qh, unsigned short* __restrict__ Ql,
    unsigned short* __restrict__ Kh, unsigned short* __restrict__ Kl,
    unsigned short* __restrict__ Vh, unsigned short* __restrict__ Vl) {
  const int tid = threadIdx.x;
  const int w = tid >> 6, l = tid & 63;
  const int m0 = blockIdx.x * 64;   // row tile (b,n flattened)
  const int h  = blockIdx.y;        // head
  const int z  = blockIdx.z;        // 0:Q 1:K 2:V
  const float* W = (z == 0) ? Wq : (z == 1) ? Wk : Wv;

  __shared__ __align__(16) unsigned short Ah[64][48], Al[64][48], Bh[64][48], Bl[64][48];

  const int rw = (w >> 1) * 32;
  const int cw = (w & 1) * 32;

  f32x4 acc[2][2] = {};

  for (int k0 = 0; k0 < 512; k0 += 32) {
    __syncthreads();
#pragma unroll
    for (int i = 0; i < 2; ++i) {
      int f = tid + i * 256;
      int row = f >> 3;
      int c4 = (f & 7) * 4;
      float4 va = *reinterpret_cast<const float4*>(&x[(size_t)(m0 + row) * 512 + k0 + c4]);
      float4 vb = *reinterpret_cast<const float4*>(&W[(size_t)(h * 64 + row) * 512 + k0 + c4]);
      unsigned short h0, l0, h1, l1, h2, l2, h3, l3;
      split_bf16(va.x, h0, l0); split_bf16(va.y, h1, l1);
      split_bf16(va.z, h2, l2); split_bf16(va.w, h3, l3);
      *reinterpret_cast<ushort4*>(&Ah[row][c4]) = make_ushort4(h0, h1, h2, h3);
      *reinterpret_cast<ushort4*>(&Al[row][c4]) = make_ushort4(l0, l1, l2, l3);
      split_bf16(vb.x, h0, l0); split_bf16(vb.y, h1, l1);
      split_bf16(vb.z, h2, l2); split_bf16(vb.w, h3, l3);
      *reinterpret_cast<ushort4*>(&Bh[row][c4]) = make_ushort4(h0, h1, h2, h3);
      *reinterpret_cast<ushort4*>(&Bl[row][c4]) = make_ushort4(l0, l1, l2, l3);
    }
    __syncthreads();

    short8 ah[2], al[2], bh[2], bl[2];
#pragma unroll
    for (int t = 0; t < 2; ++t) {
      ah[t] = *reinterpret_cast<const short8*>(&Ah[rw + t * 16 + (l & 15)][(l >> 4) * 8]);
      al[t] = *reinterpret_cast<const short8*>(&Al[rw + t * 16 + (l & 15)][(l >> 4) * 8]);
      bh[t] = *reinterpret_cast<const short8*>(&Bh[cw + t * 16 + (l & 15)][(l >> 4) * 8]);
      bl[t] = *reinterpret_cast<const short8*>(&Bl[cw + t * 16 + (l & 15)][(l >> 4) * 8]);
    }
#pragma unroll
    for (int tm = 0; tm < 2; ++tm)
#pragma unroll
      for (int tn = 0; tn < 2; ++tn) {
        acc[tm][tn] = MFMA(ah[tm], bh[tn], acc[tm][tn]);
        acc[tm][tn] = MFMA(ah[tm], bl[tn], acc[tm][tn]);
        acc[tm][tn] = MFMA(al[tm], bh[tn], acc[tm][tn]);
      }
  }

  const float qscale = 0.08838834764831845f;  // 1/sqrt(128)
#pragma unroll
  for (int tm = 0; tm < 2; ++tm)
#pragma unroll
    for (int tn = 0; tn < 2; ++tn) {
      int d = cw + tn * 16 + (l & 15);
      int mbase = m0 + rw + tm * 16 + (l >> 4) * 4;
      int b = mbase >> 11;
      int n = mbase & 2047;
      int bh = b * 8 + h;
      if (z == 2) {
        unsigned short hs[4], ls[4];
#pragma unroll
        for (int r = 0; r < 4; ++r) split_bf16(acc[tm][tn][r], hs[r], ls[r]);
        size_t idx = ((size_t)bh * 64 + d) * 2048 + n;  // n multiple of 4 -> 8B aligned
        *reinterpret_cast<ushort4*>(&Vh[idx]) = make_ushort4(hs[0], hs[1], hs[2], hs[3]);
        *reinterpret_cast<ushort4*>(&Vl[idx]) = make_ushort4(ls[0], ls[1], ls[2], ls[3]);
      } else {
        unsigned short* OH = (z == 0) ? Qh : Kh;
        unsigned short* OL = (z == 0) ? Ql : Kl;
        float sc = (z == 0) ? qscale : 1.0f;
#pragma unroll
        for (int r = 0; r < 4; ++r) {
          unsigned short hi, lo;
          split_bf16(acc[tm][tn][r] * sc, hi, lo);
          size_t idx = ((size_t)bh * 2048 + (n + r)) * 64 + d;
          OH[idx] = hi;
          OL[idx] = lo;
        }
      }
    }
}

// ---------------- Kernel 2: flash attention ----------------
// grid (16 q-tiles, 32 bh), 512 threads = 8 waves; wave w owns q rows q0+w*16..+15.
__global__ __launch_bounds__(512, 4) void attn_kernel(
    const unsigned short* __restrict__ Qh, const unsigned short* __restrict__ Ql,
    const unsigned short* __restrict__ Kh, const unsigned short* __restrict__ Kl,
    const unsigned short* __restrict__ Vh, const unsigned short* __restrict__ Vl,
    const unsigned long long* __restrict__ Mp, float* __restrict__ out) {
  const int tid = threadIdx.x;
  const int w = tid >> 6, l = tid & 63;
  const int q0 = blockIdx.x * 128;
  const int bh = blockIdx.y;
  const int b = bh >> 3, h = bh & 7;

  const unsigned short* Qhb = Qh + (size_t)bh * NSEQ * DH;
  const unsigned short* Qlb = Ql + (size_t)bh * NSEQ * DH;
  const unsigned short* Khb = Kh + (size_t)bh * NSEQ * DH;
  const unsigned short* Klb = Kl + (size_t)bh * NSEQ * DH;
  const unsigned short* Vhb = Vh + (size_t)bh * DH * NSEQ;
  const unsigned short* Vlb = Vl + (size_t)bh * DH * NSEQ;
  const unsigned long long* Mb = Mp + (size_t)b * NSEQ * 32;
  float* Ob = out + (size_t)b * NSEQ * 512 + h * 64;

  // LDS: 4 kv planes (Kh,Kl,Vh,Vl) [64][64] ushort + P hi/lo per wave [16][64].
  // All tiles XOR-swizzled (row stride 128 B, byte ^= (row&7)<<4).
  __shared__ __align__(16) unsigned short kvb[4][64][64];   // 32 KB
  __shared__ __align__(16) unsigned short pbuf[2][8][16][64]; // 32 KB

  // ---- Q fragments straight from global (contiguous 16B per lane) ----
  const size_t qrow_off = (size_t)(q0 + w * 16 + (l & 15)) * 64 + (l >> 4) * 8;
  short8 qh[2], ql[2];
#pragma unroll
  for (int dc = 0; dc < 2; ++dc) {
    qh[dc] = *reinterpret_cast<const short8*>(Qhb + qrow_off + dc * 32);
    ql[dc] = *reinterpret_cast<const short8*>(Qlb + qrow_off + dc * 32);
  }

  f32x4 o[4] = {};
  float mrun[4], lrun[4];
#pragma unroll
  for (int r = 0; r < 4; ++r) { mrun[r] = -1e30f; lrun[r] = 0.0f; }

  const int qrowbase = q0 + w * 16 + (l >> 4) * 4;
  const int srow = tid >> 3;          // staging: row 0..63
  const int scb = (tid & 7) * 16;     // staging: col byte 0..112

  for (int k0 = 0; k0 < 2048; k0 += 64) {
    __syncthreads();  // previous tile's reads done

    // ---- stage K/V hi/lo tiles: pure 16B copy per plane per thread ----
    {
      const size_t koff = (size_t)(k0 + srow) * 64 + (tid & 7) * 8;
      const size_t voff = (size_t)srow * 2048 + k0 + (tid & 7) * 8;
      short8 t0 = *reinterpret_cast<const short8*>(Khb + koff);
      short8 t1 = *reinterpret_cast<const short8*>(Klb + koff);
      short8 t2 = *reinterpret_cast<const short8*>(Vhb + voff);
      short8 t3 = *reinterpret_cast<const short8*>(Vlb + voff);
      *(short8*)lds_sw(&kvb[0][0][0], srow, scb) = t0;
      *(short8*)lds_sw(&kvb[1][0][0], srow, scb) = t1;
      *(short8*)lds_sw(&kvb[2][0][0], srow, scb) = t2;
      *(short8*)lds_sw(&kvb[3][0][0], srow, scb) = t3;
    }
    __syncthreads();

    // ---- packed mask words (broadcast within 16-lane groups) ----
    unsigned long long mw[4];
#pragma unroll
    for (int r = 0; r < 4; ++r) mw[r] = Mb[(size_t)(qrowbase + r) * 32 + (k0 >> 6)];

    // ---- S = Q K^T ----
    f32x4 s[4] = {};
#pragma unroll
    for (int dc = 0; dc < 2; ++dc) {
#pragma unroll
      for (int kt = 0; kt < 4; ++kt) {
        int row = kt * 16 + (l & 15);
        int cb = dc * 64 + (l >> 4) * 16;
        short8 kh = *(const short8*)lds_sw(&kvb[0][0][0], row, cb);
        short8 kl = *(const short8*)lds_sw(&kvb[1][0][0], row, cb);
        s[kt] = MFMA(qh[dc], kh, s[kt]);
        s[kt] = MFMA(qh[dc], kl, s[kt]);
        s[kt] = MFMA(ql[dc], kh, s[kt]);
      }
    }

    // ---- masked online softmax (row lives in a 16-lane group) ----
#pragma unroll
    for (int r = 0; r < 4; ++r) {
      float sv[4];
#pragma unroll
      for (int kt = 0; kt < 4; ++kt) {
        bool msk = (mw[r] >> (kt * 16 + (l & 15))) & 1ull;
        sv[kt] = msk ? -1e30f : s[kt][r];
      }
      float mx = fmaxf(fmaxf(sv[0], sv[1]), fmaxf(sv[2], sv[3]));
#pragma unroll
      for (int off = 1; off < 16; off <<= 1) mx = fmaxf(mx, __shfl_xor(mx, off));
      float mnew = fmaxf(mrun[r], mx);
      float scale = __expf(mrun[r] - mnew);
      float p[4], rs = 0.0f;
#pragma unroll
      for (int kt = 0; kt < 4; ++kt) {
        p[kt] = __expf(sv[kt] - mnew);  // masked: exp(-1e30-m) underflows to 0
        rs += p[kt];
      }
#pragma unroll
      for (int off = 1; off < 16; off <<= 1) rs += __shfl_xor(rs, off);
      lrun[r] = lrun[r] * scale + rs;
      mrun[r] = mnew;
#pragma unroll
      for (int dt = 0; dt < 4; ++dt) o[dt][r] *= scale;

      int prow = (l >> 4) * 4 + r;
#pragma unroll
      for (int kt = 0; kt < 4; ++kt) {
        unsigned short hi, lo;
        split_bf16(p[kt], hi, lo);
        *(unsigned short*)lds_sw(&pbuf[0][w][0][0], prow, (kt * 16 + (l & 15)) * 2) = hi;
        *(unsigned short*)lds_sw(&pbuf[1][w][0][0], prow, (kt * 16 + (l & 15)) * 2) = lo;
      }
    }

    // ---- O += P V (same-wave LDS write->read; compiler inserts lgkmcnt) ----
    short8 pah[2], pal[2];
#pragma unroll
    for (int kc = 0; kc < 2; ++kc) {
      int cb = kc * 64 + (l >> 4) * 16;
      pah[kc] = *(const short8*)lds_sw(&pbuf[0][w][0][0], l & 15, cb);
      pal[kc] = *(const short8*)lds_sw(&pbuf[1][w][0][0], l & 15, cb);
    }
#pragma unroll
    for (int dt = 0; dt < 4; ++dt) {
#pragma unroll
      for (int kc = 0; kc < 2; ++kc) {
        int row = dt * 16 + (l & 15);
        int cb = kc * 64 + (l >> 4) * 16;
        short8 vh = *(const short8*)lds_sw(&kvb[2][0][0], row, cb);
        short8 vl = *(const short8*)lds_sw(&kvb[3][0][0], row, cb);
        o[dt] = MFMA(pah[kc], vh, o[dt]);
        o[dt] = MFMA(pah[kc], vl, o[dt]);
        o[dt] = MFMA(pal[kc], vh, o[dt]);
      }
    }
  }

  // ---- epilogue ----
#pragma unroll
  for (int r = 0; r < 4; ++r) {
    float invl = lrun[r] > 0.0f ? 1.0f / lrun[r] : 0.0f;
    int qrow = qrowbase + r;
#pragma unroll
    for (int dt = 0; dt < 4; ++dt) {
      Ob[(size_t)qrow * 512 + dt * 16 + (l & 15)] = o[dt][r] * invl;
    }
  }
}

extern "C" void kernel_launch(void* const* d_in, const int* in_sizes, int n_in,
                              void* d_out, int out_size, void* d_ws, size_t ws_size,
                              hipStream_t stream) {
  const float* x = (const float*)d_in[0];
  const void* mask = d_in[1];
  const float* Wq = (const float*)d_in[2];
  const float* Wk = (const float*)d_in[3];
  const float* Wv = (const float*)d_in[4];
  float* out = (float*)d_out;

  const size_t PLANE = (size_t)NBH * NSEQ * DH;  // 4,194,304 ushorts per plane
  unsigned short* Qh = (unsigned short*)d_ws;
  unsigned short* Ql = Qh + PLANE;
  unsigned short* Kh = Ql + PLANE;
  unsigned short* Kl = Kh + PLANE;
  unsigned short* Vh = Kl + PLANE;
  unsigned short* Vl = Vh + PLANE;
  unsigned long long* Mp = (unsigned long long*)(Vl + PLANE);  // 262,144 words (2 MB)

  pack_mask<<<65536, 256, 0, stream>>>(mask, Mp);
  proj_kernel<<<dim3(128, 8, 3), 256, 0, stream>>>(x, Wq, Wk, Wv, Qh, Ql, Kh, Kl, Vh, Vl);
  attn_kernel<<<dim3(16, 32), 512, 0, stream>>>(Qh, Ql, Kh, Kl, Vh, Vl, Mp, out);
}

// Round 5
// 196.842 us; speedup vs baseline: 1.7109x; 1.4103x over previous
//
#include <hip/hip_runtime.h>

// Attention_29231547416680: B=4, N=2048, CH=512, H=8, D=64, fp32 in/out.
// R5 = R4 with the P-buffer write-offset bug fixed (kt*256 -> proper swizzled
//      kt*64) and a bounds-safe mask dtype probe.

typedef float f32x4 __attribute__((ext_vector_type(4)));
typedef short short8 __attribute__((ext_vector_type(8)));

#define MFMA(a, b, c) __builtin_amdgcn_mfma_f32_16x16x32_bf16((a), (b), (c), 0, 0, 0)

#if __has_builtin(__builtin_amdgcn_exp2f)
#define EXP2(x) __builtin_amdgcn_exp2f(x)
#else
#define EXP2(x) exp2f(x)
#endif

#define NBH 32
#define NSEQ 2048
#define DH 64

__device__ __forceinline__ unsigned short f2bf(float f) {
  unsigned int u = __float_as_uint(f);
  u += 0x7fffu + ((u >> 16) & 1u);  // RTNE
  return (unsigned short)(u >> 16);
}
__device__ __forceinline__ float bf2f(unsigned short h) {
  return __uint_as_float(((unsigned int)h) << 16);
}
__device__ __forceinline__ void split_bf16(float f, unsigned short& hi, unsigned short& lo) {
  hi = f2bf(f);
  lo = f2bf(f - bf2f(hi));
}

// packed dword: bf16(hi) in low16, bf16(lo, truncated split) in high16
__device__ __forceinline__ unsigned pack_hilo(float p) {
  unsigned u = __float_as_uint(p);
  float lo = p - __uint_as_float(u & 0xffff0000u);
  unsigned ul = __float_as_uint(lo);
#if __has_builtin(__builtin_amdgcn_perm)
  return __builtin_amdgcn_perm(ul, u, 0x07060302u);
#else
  return (u >> 16) | (ul & 0xffff0000u);
#endif
}
__device__ __forceinline__ unsigned lo16pair(unsigned d0, unsigned d1) {
#if __has_builtin(__builtin_amdgcn_perm)
  return __builtin_amdgcn_perm(d1, d0, 0x05040100u);
#else
  return (d0 & 0xffffu) | (d1 << 16);
#endif
}
__device__ __forceinline__ unsigned hi16pair(unsigned d0, unsigned d1) {
#if __has_builtin(__builtin_amdgcn_perm)
  return __builtin_amdgcn_perm(d1, d0, 0x07060302u);
#else
  return (d0 >> 16) | (d1 & 0xffff0000u);
#endif
}

// ---------------- mask bit-pack: 1024 blocks, thread owns 64 elems ----------------
__global__ __launch_bounds__(256) void pack_mask(const void* __restrict__ mraw,
                                                 unsigned long long* __restrict__ Mp) {
  const int tid = threadIdx.x;
  __shared__ int s_bad;
  if (tid == 0) s_bad = 0;
  __syncthreads();
  const unsigned int* mw32 = (const unsigned int*)mraw;
  {
    // probe the first 2 KB only (in-bounds for both 1B and 4B encodings)
    unsigned int w0 = mw32[tid], w1 = mw32[256 + tid];
    bool ok = (w0 == 0u || w0 == 1u || w0 == 0x3f800000u) &&
              (w1 == 0u || w1 == 1u || w1 == 0x3f800000u);
    if (!ok) s_bad = 1;
  }
  __syncthreads();
  const size_t e0 = (size_t)blockIdx.x * 16384 + (size_t)tid * 64;
  unsigned long long bits = 0ull;
  if (s_bad == 0) {
    const uint4* p = (const uint4*)mw32 + (e0 >> 2);
#pragma unroll
    for (int j = 0; j < 16; ++j) {
      uint4 v = p[j];
      unsigned nib = (v.x != 0u) | ((v.y != 0u) << 1) | ((v.z != 0u) << 2) | ((v.w != 0u) << 3);
      bits |= (unsigned long long)nib << (j * 4);
    }
  } else {
    const uint4* p = (const uint4*)((const unsigned char*)mraw + e0);
#pragma unroll
    for (int j = 0; j < 4; ++j) {
      uint4 v = p[j];
      unsigned dw[4] = {v.x, v.y, v.z, v.w};
#pragma unroll
      for (int d = 0; d < 4; ++d) {
        unsigned nib = (((dw[d]) & 0xffu) != 0u) | ((((dw[d] >> 8) & 0xffu) != 0u) << 1) |
                       ((((dw[d] >> 16) & 0xffu) != 0u) << 2) | ((((dw[d] >> 24) & 0xffu) != 0u) << 3);
        bits |= (unsigned long long)nib << ((j * 4 + d) * 4);
      }
    }
  }
  Mp[e0 >> 6] = bits;
}

// ---------------- Kernel 1: QKV projection (z-merged) ----------------
// Q pre-scaled by log2(e)/sqrt(128); Q,K: [bh][n][64] hi/lo; V: [bh][64][n] hi/lo.
__global__ __launch_bounds__(256) void proj_kernel(
    const float* __restrict__ x,
    const float* __restrict__ Wq, const float* __restrict__ Wk, const float* __restrict__ Wv,
    unsigned short* __restrict__ Qh, unsigned short* __restrict__ Ql,
    unsigned short* __restrict__ Kh, unsigned short* __restrict__ Kl,
    unsigned short* __restrict__ Vh, unsigned short* __restrict__ Vl) {
  const int tid = threadIdx.x;
  const int w = tid >> 6, l = tid & 63;
  const int m0 = blockIdx.x * 64;
  const int h = blockIdx.y;
  const int lrow = l & 15, lg = l >> 4;
  const int rw = (w >> 1) * 32, cw = (w & 1) * 32;

  union LDSU {
    struct {
      unsigned short Ah[64][48], Al[64][48];
      unsigned short Bh[3][64][48], Bl[3][64][48];
    } s;
    unsigned short ob[6][64][72];  // epilogue bounce (row stride 144B, 16B aligned)
  };
  __shared__ LDSU u;

  f32x4 acc[3][2][2] = {};
  const int srow = tid >> 2, sc8 = (tid & 3) * 8;

  for (int k0 = 0; k0 < 512; k0 += 32) {
    __syncthreads();
    {
      const float* xs = &x[(size_t)(m0 + srow) * 512 + k0 + sc8];
      float4 a0 = *(const float4*)xs, a1 = *(const float4*)(xs + 4);
      unsigned short h0, l0, h1, l1, h2, l2, h3, l3;
      split_bf16(a0.x, h0, l0); split_bf16(a0.y, h1, l1);
      split_bf16(a0.z, h2, l2); split_bf16(a0.w, h3, l3);
      *(ushort4*)&u.s.Ah[srow][sc8] = make_ushort4(h0, h1, h2, h3);
      *(ushort4*)&u.s.Al[srow][sc8] = make_ushort4(l0, l1, l2, l3);
      split_bf16(a1.x, h0, l0); split_bf16(a1.y, h1, l1);
      split_bf16(a1.z, h2, l2); split_bf16(a1.w, h3, l3);
      *(ushort4*)&u.s.Ah[srow][sc8 + 4] = make_ushort4(h0, h1, h2, h3);
      *(ushort4*)&u.s.Al[srow][sc8 + 4] = make_ushort4(l0, l1, l2, l3);
      const float* Wz[3] = {Wq, Wk, Wv};
#pragma unroll
      for (int z = 0; z < 3; ++z) {
        const float* ws = &Wz[z][(size_t)(h * 64 + srow) * 512 + k0 + sc8];
        float4 b0 = *(const float4*)ws, b1 = *(const float4*)(ws + 4);
        split_bf16(b0.x, h0, l0); split_bf16(b0.y, h1, l1);
        split_bf16(b0.z, h2, l2); split_bf16(b0.w, h3, l3);
        *(ushort4*)&u.s.Bh[z][srow][sc8] = make_ushort4(h0, h1, h2, h3);
        *(ushort4*)&u.s.Bl[z][srow][sc8] = make_ushort4(l0, l1, l2, l3);
        split_bf16(b1.x, h0, l0); split_bf16(b1.y, h1, l1);
        split_bf16(b1.z, h2, l2); split_bf16(b1.w, h3, l3);
        *(ushort4*)&u.s.Bh[z][srow][sc8 + 4] = make_ushort4(h0, h1, h2, h3);
        *(ushort4*)&u.s.Bl[z][srow][sc8 + 4] = make_ushort4(l0, l1, l2, l3);
      }
    }
    __syncthreads();

    short8 ah[2], al[2];
#pragma unroll
    for (int t = 0; t < 2; ++t) {
      ah[t] = *(const short8*)&u.s.Ah[rw + 16 * t + lrow][lg * 8];
      al[t] = *(const short8*)&u.s.Al[rw + 16 * t + lrow][lg * 8];
    }
#pragma unroll
    for (int z = 0; z < 3; ++z) {
      short8 bh[2], bl[2];
#pragma unroll
      for (int t = 0; t < 2; ++t) {
        bh[t] = *(const short8*)&u.s.Bh[z][cw + 16 * t + lrow][lg * 8];
        bl[t] = *(const short8*)&u.s.Bl[z][cw + 16 * t + lrow][lg * 8];
      }
#pragma unroll
      for (int tm = 0; tm < 2; ++tm)
#pragma unroll
        for (int tn = 0; tn < 2; ++tn) {
          acc[z][tm][tn] = MFMA(ah[tm], bh[tn], acc[z][tm][tn]);
          acc[z][tm][tn] = MFMA(ah[tm], bl[tn], acc[z][tm][tn]);
          acc[z][tm][tn] = MFMA(al[tm], bh[tn], acc[z][tm][tn]);
        }
    }
  }

  __syncthreads();  // staging LDS dead; reuse as obuf
  const float qsc = 1.4426950408889634f * 0.08838834764831845f;  // log2e/sqrt(128)
#pragma unroll
  for (int z = 0; z < 3; ++z)
#pragma unroll
    for (int tm = 0; tm < 2; ++tm)
#pragma unroll
      for (int tn = 0; tn < 2; ++tn) {
        int d = cw + tn * 16 + lrow;
        int nl = rw + tm * 16 + lg * 4;
#pragma unroll
        for (int r = 0; r < 4; ++r) {
          float v = acc[z][tm][tn][r];
          if (z == 0) v *= qsc;
          unsigned short hi, lo;
          split_bf16(v, hi, lo);
          if (z < 2) {
            u.ob[2 * z][nl + r][d] = hi;
            u.ob[2 * z + 1][nl + r][d] = lo;
          } else {
            u.ob[4][d][nl + r] = hi;
            u.ob[5][d][nl + r] = lo;
          }
        }
      }
  __syncthreads();

  const int orow = tid >> 2, oc = (tid & 3) * 16;
  const int b = m0 >> 11, n0 = m0 & 2047, bhid = b * 8 + h;
  {
    unsigned short* QK[4] = {Qh, Ql, Kh, Kl};
#pragma unroll
    for (int p = 0; p < 4; ++p) {
      size_t base = ((size_t)bhid * 2048 + n0 + orow) * 64 + oc;
      *(short8*)&QK[p][base] = *(const short8*)&u.ob[p][orow][oc];
      *(short8*)&QK[p][base + 8] = *(const short8*)&u.ob[p][orow][oc + 8];
    }
    unsigned short* VV[2] = {Vh, Vl};
#pragma unroll
    for (int p = 0; p < 2; ++p) {
      size_t vb = ((size_t)bhid * 64 + orow) * 2048 + n0 + oc;
      *(short8*)&VV[p][vb] = *(const short8*)&u.ob[4 + p][orow][oc];
      *(short8*)&VV[p][vb + 8] = *(const short8*)&u.ob[4 + p][orow][oc + 8];
    }
  }
}

// ---------------- Kernel 2: flash attention ----------------
// 512 blocks (XCD-swizzled), 512 threads = 8 waves; wave w owns q rows q0+w*16..+15.
__global__ __launch_bounds__(512, 4) void attn_kernel(
    const unsigned short* __restrict__ Qh, const unsigned short* __restrict__ Ql,
    const unsigned short* __restrict__ Kh, const unsigned short* __restrict__ Kl,
    const unsigned short* __restrict__ Vh, const unsigned short* __restrict__ Vl,
    const unsigned long long* __restrict__ Mp, float* __restrict__ out) {
  const int tid = threadIdx.x;
  const int w = tid >> 6, l = tid & 63;
  // XCD swizzle: 64 consecutive remapped ids (4 whole bh) per XCD
  const int wl = blockIdx.x;
  const int rm = (wl & 7) * 64 + (wl >> 3);
  const int q0 = (rm & 15) * 128;
  const int bh = rm >> 4;
  const int b = bh >> 3, h = bh & 7;
  const int lrow = l & 15, lg = l >> 4, lsw = (l & 7) << 4;

  const unsigned short* Qhb = Qh + (size_t)bh * NSEQ * DH;
  const unsigned short* Qlb = Ql + (size_t)bh * NSEQ * DH;
  const unsigned short* Khb = Kh + (size_t)bh * NSEQ * DH;
  const unsigned short* Klb = Kl + (size_t)bh * NSEQ * DH;
  const unsigned short* Vhb = Vh + (size_t)bh * DH * NSEQ;
  const unsigned short* Vlb = Vl + (size_t)bh * DH * NSEQ;
  const unsigned long long* Mb = Mp + (size_t)b * NSEQ * 32;
  float* Ob = out + (size_t)b * NSEQ * 512 + h * 64;

  __shared__ __align__(16) unsigned short kvb[4][64][64];  // Kh,Kl,Vh,Vl swizzled, 32KB
  __shared__ __align__(16) unsigned int pb[8][16][64];     // packed P per wave, 32KB

  char* kv0 = (char*)&kvb[0][0][0];
  char* pbw = (char*)&pb[0][0][0] + w * 4096;

  // hoisted swizzled LDS offsets (all loop-invariant)
  const int rb0 = lrow * 128 + ((lg * 16) ^ lsw);        // dc/kc = 0
  const int rb1 = lrow * 128 + ((64 + lg * 16) ^ lsw);   // dc/kc = 1
  int pwoff[4];  // P write: full linear offset XOR'd (avoids XOR+add carry bug)
#pragma unroll
  for (int kt = 0; kt < 4; ++kt) pwoff[kt] = (lrow * 256 + kt * 64 + lg * 16) ^ lsw;
  const int pr0 = lrow * 256 + ((lg * 32) ^ lsw);        // P read, first 16B (+kc*128)
  const int pr1 = lrow * 256 + (((lg * 32) + 16) ^ lsw); // P read, second 16B

  // Q fragments (B-operand): row = q0+w*16+lrow, k = lg*8 (+dc*32)
  const size_t qoff = (size_t)(q0 + w * 16 + lrow) * 64 + lg * 8;
  short8 qh[2], ql[2];
#pragma unroll
  for (int dc = 0; dc < 2; ++dc) {
    qh[dc] = *(const short8*)(Qhb + qoff + dc * 32);
    ql[dc] = *(const short8*)(Qlb + qoff + dc * 32);
  }

  f32x4 o[4] = {};
  float mrun = -1e30f, lrun = 0.0f;  // per lane: softmax state of q-row (l&15)
  const int qglob = q0 + w * 16 + lrow;

  // async staging: tile t loaded into regs during tile t-1's compute
  const int stg_row = tid >> 3, stg_c = (tid & 7) * 8;
  const int sdst = stg_row * 128 + ((stg_c * 2) ^ ((stg_row & 7) << 4));
  size_t koff = (size_t)stg_row * 64 + stg_c;
  size_t voff = (size_t)stg_row * 2048 + stg_c;
  short8 st0 = *(const short8*)(Khb + koff);
  short8 st1 = *(const short8*)(Klb + koff);
  short8 st2 = *(const short8*)(Vhb + voff);
  short8 st3 = *(const short8*)(Vlb + voff);

  for (int k0 = 0; k0 < 2048; k0 += 64) {
    __syncthreads();  // all waves done reading previous tile
    *(short8*)(kv0 + sdst) = st0;
    *(short8*)(kv0 + sdst + 8192) = st1;
    *(short8*)(kv0 + sdst + 16384) = st2;
    *(short8*)(kv0 + sdst + 24576) = st3;
    __syncthreads();
    if (k0 < 2048 - 64) {  // prefetch next tile into regs (latency hidden by compute)
      koff += 4096; voff += 64;
      st0 = *(const short8*)(Khb + koff);
      st1 = *(const short8*)(Klb + koff);
      st2 = *(const short8*)(Vhb + voff);
      st3 = *(const short8*)(Vlb + voff);
    }

    // ---- S^T = K Q^T : lane holds S[k=kt*16+lg*4+r][q=lrow] ----
    f32x4 s[4] = {};
#pragma unroll
    for (int dc = 0; dc < 2; ++dc) {
      const int rb = dc ? rb1 : rb0;
#pragma unroll
      for (int kt = 0; kt < 4; ++kt) {
        short8 kh = *(const short8*)(kv0 + rb + kt * 2048);
        short8 kl = *(const short8*)(kv0 + rb + kt * 2048 + 8192);
        s[kt] = MFMA(kh, qh[dc], s[kt]);
        s[kt] = MFMA(kh, ql[dc], s[kt]);
        s[kt] = MFMA(kl, qh[dc], s[kt]);
      }
    }

    // ---- mask + lane-local online softmax (exp2 domain) ----
    const unsigned long long mw = Mb[(size_t)qglob * 32 + (k0 >> 6)];
#pragma unroll
    for (int kt = 0; kt < 4; ++kt) {
      unsigned nib = ((unsigned)(mw >> (kt * 16 + lg * 4))) & 0xFu;
#pragma unroll
      for (int r = 0; r < 4; ++r) s[kt][r] = ((nib >> r) & 1u) ? -1e30f : s[kt][r];
    }
    float mx = s[0][0];
#pragma unroll
    for (int kt = 0; kt < 4; ++kt)
#pragma unroll
      for (int r = 0; r < 4; ++r) mx = fmaxf(mx, s[kt][r]);
    mx = fmaxf(mx, __shfl_xor(mx, 16));
    mx = fmaxf(mx, __shfl_xor(mx, 32));
    const bool grow = __any(mx > mrun + 11.0f);  // defer-max: p bounded by 2^11
    const float mnew = grow ? fmaxf(mrun, mx) : mrun;

    float rs = 0.0f;
#pragma unroll
    for (int kt = 0; kt < 4; ++kt) {
      float p0 = EXP2(s[kt][0] - mnew);
      float p1 = EXP2(s[kt][1] - mnew);
      float p2 = EXP2(s[kt][2] - mnew);
      float p3 = EXP2(s[kt][3] - mnew);
      rs += (p0 + p1) + (p2 + p3);
      uint4 pk = make_uint4(pack_hilo(p0), pack_hilo(p1), pack_hilo(p2), pack_hilo(p3));
      *(uint4*)(pbw + pwoff[kt]) = pk;
    }
    rs += __shfl_xor(rs, 16);
    rs += __shfl_xor(rs, 32);
    if (grow) {
      float sc = EXP2(mrun - mnew);
      lrun = lrun * sc + rs;
      mrun = mnew;
#pragma unroll
      for (int r = 0; r < 4; ++r) {
        float so = __shfl(sc, lg * 4 + r);
#pragma unroll
        for (int dt = 0; dt < 4; ++dt) o[dt][r] *= so;
      }
    } else {
      lrun += rs;
    }

    // ---- O += P V  (P from packed dwords; same-wave LDS write->read) ----
    short8 pah[2], pal[2];
#pragma unroll
    for (int kc = 0; kc < 2; ++kc) {
      uint4 d0 = *(const uint4*)(pbw + pr0 + kc * 128);
      uint4 d1 = *(const uint4*)(pbw + pr1 + kc * 128);
      union PS { uint4 q; short8 s; } H, L;
      H.q.x = lo16pair(d0.x, d0.y); H.q.y = lo16pair(d0.z, d0.w);
      H.q.z = lo16pair(d1.x, d1.y); H.q.w = lo16pair(d1.z, d1.w);
      L.q.x = hi16pair(d0.x, d0.y); L.q.y = hi16pair(d0.z, d0.w);
      L.q.z = hi16pair(d1.x, d1.y); L.q.w = hi16pair(d1.z, d1.w);
      pah[kc] = H.s;
      pal[kc] = L.s;
    }
#pragma unroll
    for (int dt = 0; dt < 4; ++dt) {
#pragma unroll
      for (int kc = 0; kc < 2; ++kc) {
        const int rb = kc ? rb1 : rb0;
        short8 vh = *(const short8*)(kv0 + rb + dt * 2048 + 16384);
        short8 vl = *(const short8*)(kv0 + rb + dt * 2048 + 24576);
        o[dt] = MFMA(pah[kc], vh, o[dt]);
        o[dt] = MFMA(pah[kc], vl, o[dt]);
        o[dt] = MFMA(pal[kc], vh, o[dt]);
      }
    }
  }

  // ---- epilogue: redistribute 1/l and store ----
#pragma unroll
  for (int r = 0; r < 4; ++r) {
    float lr = __shfl(lrun, lg * 4 + r);
    float invl = lr > 0.0f ? 1.0f / lr : 0.0f;
    int qrow = q0 + w * 16 + lg * 4 + r;
#pragma unroll
    for (int dt = 0; dt < 4; ++dt) {
      Ob[(size_t)qrow * 512 + dt * 16 + lrow] = o[dt][r] * invl;
    }
  }
}

extern "C" void kernel_launch(void* const* d_in, const int* in_sizes, int n_in,
                              void* d_out, int out_size, void* d_ws, size_t ws_size,
                              hipStream_t stream) {
  const float* x = (const float*)d_in[0];
  const void* mask = d_in[1];
  const float* Wq = (const float*)d_in[2];
  const float* Wk = (const float*)d_in[3];
  const float* Wv = (const float*)d_in[4];
  float* out = (float*)d_out;

  const size_t PLANE = (size_t)NBH * NSEQ * DH;  // 4,194,304 ushorts
  unsigned short* Qh = (unsigned short*)d_ws;
  unsigned short* Ql = Qh + PLANE;
  unsigned short* Kh = Ql + PLANE;
  unsigned short* Kl = Kh + PLANE;
  unsigned short* Vh = Kl + PLANE;
  unsigned short* Vl = Vh + PLANE;
  unsigned long long* Mp = (unsigned long long*)(Vl + PLANE);  // 2 MB

  pack_mask<<<1024, 256, 0, stream>>>(mask, Mp);
  proj_kernel<<<dim3(128, 8), 256, 0, stream>>>(x, Wq, Wk, Wv, Qh, Ql, Kh, Kl, Vh, Vl);
  attn_kernel<<<512, 512, 0, stream>>>(Qh, Ql, Kh, Kl, Vh, Vl, Mp, out);
}